// Round 1
// baseline (506.640 us; speedup 1.0000x reference)
//
#include <hip/hip_runtime.h>
#include <math.h>

// Problem constants (B, N, M, V, T fixed by reference)
namespace {
constexpr int kB = 8;
constexpr int kN = 6;        // max_span
constexpr int kM = 64;
constexpr int kV = 32000;
constexpr int kT = 8;        // template_len
constexpr int kS = kN + 1;   // 7
constexpr int kV4 = kV / 4;  // 8000 float4 per row
constexpr int kThreads = 256;
}  // namespace

// ws layout: int len_raw[B*T]; int sel[B*M];
__global__ void init_ws_kernel(int* __restrict__ len_raw) {
  int i = threadIdx.x;
  if (i < kB * kT) len_raw[i] = kM;
}

// ---------------------------------------------------------------------------
// Pass 1: per (b,m) block, stream the `nuse = spans[b]` used input rows once.
// For each t: out_t[b,m,v] = sum_n w[t][n]*in[b,n,m,v] (+w0[t] at m==0,v==0).
// Track block max per t and the v==0 value; argmax==0 iff v0 >= max.
// Also speculatively store the t==0 row to d_out (usual final answer).
// ---------------------------------------------------------------------------
template <int NUSE>
__device__ __forceinline__ void pass1_body(const float* __restrict__ in,
                                           const float* __restrict__ tw,  // tmpl + b*T*S
                                           float* __restrict__ orow,
                                           int b, int m,
                                           int* __restrict__ len_raw) {
  const int tid = threadIdx.x;
  constexpr int NA = NUSE > 0 ? NUSE : 1;

  float w[kT][NA];
  float w0[kT];
#pragma unroll
  for (int t = 0; t < kT; ++t) {
    w0[t] = tw[t * kS];  // s=0 pad weight (always unmasked since span>=0)
#pragma unroll
    for (int n = 0; n < NUSE; ++n) w[t][n] = tw[t * kS + n + 1];
  }

  const float4* rows[NA];
#pragma unroll
  for (int n = 0; n < NUSE; ++n)
    rows[n] = (const float4*)(in + ((size_t)(b * kN + n) * kM + m) * kV);

  float mx[kT], v0[kT];
#pragma unroll
  for (int t = 0; t < kT; ++t) {
    mx[t] = -INFINITY;
    v0[t] = 0.0f;
  }

  for (int v4 = tid; v4 < kV4; v4 += kThreads) {
    float4 x[NA];
#pragma unroll
    for (int n = 0; n < NUSE; ++n) x[n] = rows[n][v4];
    const bool head = (v4 == 0);  // only tid 0, first iteration
#pragma unroll
    for (int t = 0; t < kT; ++t) {
      float ax = 0.0f, ay = 0.0f, az = 0.0f, aw = 0.0f;
#pragma unroll
      for (int n = 0; n < NUSE; ++n) {
        ax = fmaf(w[t][n], x[n].x, ax);
        ay = fmaf(w[t][n], x[n].y, ay);
        az = fmaf(w[t][n], x[n].z, az);
        aw = fmaf(w[t][n], x[n].w, aw);
      }
      if (head && m == 0) ax += w0[t];  // pad one-hot lands at (m=0,v=0)
      if (head) v0[t] = ax;
      mx[t] = fmaxf(mx[t], fmaxf(fmaxf(ax, ay), fmaxf(az, aw)));
      if (t == 0) ((float4*)orow)[v4] = make_float4(ax, ay, az, aw);
    }
  }

  // Block max reduction per t: wave shuffle, then 4 wave results via LDS.
  __shared__ float red[kT][4];
  const int lane = tid & 63;
  const int wv = tid >> 6;
#pragma unroll
  for (int t = 0; t < kT; ++t) {
    float v = mx[t];
#pragma unroll
    for (int off = 32; off > 0; off >>= 1) v = fmaxf(v, __shfl_xor(v, off, 64));
    if (lane == 0) red[t][wv] = v;
  }
  __syncthreads();
  if (tid == 0) {
#pragma unroll
    for (int t = 0; t < kT; ++t) {
      float bm = fmaxf(fmaxf(red[t][0], red[t][1]), fmaxf(red[t][2], red[t][3]));
      // v0 attains the block max  <=>  argmax over v is 0 (first occurrence)
      if (v0[t] >= bm) atomicMin(&len_raw[b * kT + t], m);
    }
  }
}

__global__ __launch_bounds__(kThreads) void pass1_kernel(
    const float* __restrict__ in, const float* __restrict__ tmpl,
    const int* __restrict__ spans, float* __restrict__ out,
    int* __restrict__ len_raw) {
  const int blk = blockIdx.x;
  const int b = blk >> 6;
  const int m = blk & 63;
  int span = spans[b];
  int nuse = span < 0 ? 0 : (span > kN ? kN : span);  // rows used: n < span
  const float* tw = tmpl + (size_t)b * kT * kS;
  float* orow = out + (size_t)(b * kM + m) * kV;
  switch (nuse) {
    case 0: pass1_body<0>(in, tw, orow, b, m, len_raw); break;
    case 1: pass1_body<1>(in, tw, orow, b, m, len_raw); break;
    case 2: pass1_body<2>(in, tw, orow, b, m, len_raw); break;
    case 3: pass1_body<3>(in, tw, orow, b, m, len_raw); break;
    case 4: pass1_body<4>(in, tw, orow, b, m, len_raw); break;
    case 5: pass1_body<5>(in, tw, orow, b, m, len_raw); break;
    case 6: pass1_body<6>(in, tw, orow, b, m, len_raw); break;
  }
}

// ---------------------------------------------------------------------------
// Pass 2: tiny sequential scan per b. sel[b][m] = t*64 + src_row, or -1.
// ---------------------------------------------------------------------------
__global__ void pass2_kernel(const int* __restrict__ len_raw,
                             int* __restrict__ sel) {
  int b = threadIdx.x;
  if (b >= kB) return;
  for (int m = 0; m < kM; ++m) sel[b * kM + m] = -1;
  int idx = 0;
  for (int t = 0; t < kT; ++t) {
    int L = len_raw[b * kT + t];  // first m with argmax==0, else M
    if (L > kM - idx) L = kM - idx;
    for (int j = 0; j < L; ++j) sel[b * kM + idx + j] = t * 64 + j;
    idx += L;
  }
}

// ---------------------------------------------------------------------------
// Pass 3: patch rows whose selection is not (t=0, row=m).
// sel in [0,64) => t==0 (then row==m by construction): pass1 already wrote it.
// sel == -1 => result row stays zero. Otherwise recompute the selected row.
// ---------------------------------------------------------------------------
__global__ __launch_bounds__(kThreads) void pass3_kernel(
    const float* __restrict__ in, const float* __restrict__ tmpl,
    const int* __restrict__ spans, const int* __restrict__ sel,
    float* __restrict__ out) {
  const int blk = blockIdx.x;
  const int b = blk >> 6;
  const int m = blk & 63;
  const int s = sel[b * kM + m];
  if (s >= 0 && s < 64) return;  // t==0 row, already stored by pass1

  const int tid = threadIdx.x;
  float* orow = out + (size_t)(b * kM + m) * kV;

  if (s < 0) {  // never written by the scan -> zeros
    float4 z = make_float4(0.0f, 0.0f, 0.0f, 0.0f);
    for (int v4 = tid; v4 < kV4; v4 += kThreads) ((float4*)orow)[v4] = z;
    return;
  }

  const int t = s >> 6;
  const int row = s & 63;
  int span = spans[b];
  int nuse = span < 0 ? 0 : (span > kN ? kN : span);
  const float* tw = tmpl + ((size_t)b * kT + t) * kS;
  const float w0 = tw[0];
  float w[kN];
  for (int n = 0; n < kN; ++n) w[n] = (n < nuse) ? tw[n + 1] : 0.0f;

  const float4* rows[kN];
  for (int n = 0; n < kN; ++n)
    rows[n] = (const float4*)(in + ((size_t)(b * kN + n) * kM + row) * kV);

  for (int v4 = tid; v4 < kV4; v4 += kThreads) {
    float ax = 0.0f, ay = 0.0f, az = 0.0f, aw = 0.0f;
    for (int n = 0; n < nuse; ++n) {
      float4 x = rows[n][v4];
      ax = fmaf(w[n], x.x, ax);
      ay = fmaf(w[n], x.y, ay);
      az = fmaf(w[n], x.z, az);
      aw = fmaf(w[n], x.w, aw);
    }
    if (v4 == 0 && row == 0) ax += w0;
    ((float4*)orow)[v4] = make_float4(ax, ay, az, aw);
  }
}

extern "C" void kernel_launch(void* const* d_in, const int* in_sizes, int n_in,
                              void* d_out, int out_size, void* d_ws,
                              size_t ws_size, hipStream_t stream) {
  const float* in = (const float*)d_in[0];     // [B,N,M,V] f32
  const float* tmpl = (const float*)d_in[1];   // [B,T,N+1] f32
  const int* spans = (const int*)d_in[2];      // [B] i32
  float* out = (float*)d_out;                  // [B,M,V] f32

  int* len_raw = (int*)d_ws;          // B*T ints
  int* sel = len_raw + kB * kT;       // B*M ints

  hipLaunchKernelGGL(init_ws_kernel, dim3(1), dim3(64), 0, stream, len_raw);
  hipLaunchKernelGGL(pass1_kernel, dim3(kB * kM), dim3(kThreads), 0, stream,
                     in, tmpl, spans, out, len_raw);
  hipLaunchKernelGGL(pass2_kernel, dim3(1), dim3(64), 0, stream, len_raw, sel);
  hipLaunchKernelGGL(pass3_kernel, dim3(kB * kM), dim3(kThreads), 0, stream,
                     in, tmpl, spans, sel, out);
}

// Round 2
// 485.500 us; speedup vs baseline: 1.0435x; 1.0435x over previous
//
#include <hip/hip_runtime.h>
#include <math.h>

// Problem constants (B, N, M, V, T fixed by reference)
namespace {
constexpr int kB = 8;
constexpr int kN = 6;        // max_span
constexpr int kM = 64;
constexpr int kV = 32000;
constexpr int kT = 8;        // template_len
constexpr int kS = kN + 1;   // 7
constexpr int kV4 = kV / 4;  // 8000 float4 per row
constexpr int kThreads = 256;
}  // namespace

typedef float f32x4 __attribute__((ext_vector_type(4)));

// ws layout: int flags[B*T*M]  (flag[b][t][m] = 1 iff argmax_v out_t[b,m,:] == 0)
// Every slot is written exactly once by pass1 -> no init kernel, no atomics.

// ---------------------------------------------------------------------------
// Pass 1: per (b,m) block, stream the `nuse = spans[b]` used input rows once.
// For each t: out_t[b,m,v] = sum_n w[t][n]*in[b,n,m,v] (+w0[t] at m==0,v==0).
// argmax_v == 0  <=>  value at v=0 attains the row max (first occurrence).
// Speculatively store the t==0 row to d_out (statistically the final answer).
// ---------------------------------------------------------------------------
template <int NUSE>
__device__ __forceinline__ void pass1_body(const float* __restrict__ in,
                                           const float* __restrict__ tw,  // tmpl + b*T*S
                                           float* __restrict__ orow,
                                           int b, int m,
                                           int* __restrict__ flags) {
  const int tid = threadIdx.x;
  constexpr int NA = NUSE > 0 ? NUSE : 1;

  float w[kT][NA];
  float w0[kT];
#pragma unroll
  for (int t = 0; t < kT; ++t) {
    w0[t] = tw[t * kS];  // s=0 pad weight (always unmasked since span>=0)
#pragma unroll
    for (int n = 0; n < NUSE; ++n) w[t][n] = tw[t * kS + n + 1];
  }

  const f32x4* rows[NA];
#pragma unroll
  for (int n = 0; n < NUSE; ++n)
    rows[n] = (const f32x4*)(in + ((size_t)(b * kN + n) * kM + m) * kV);

  f32x4* orow4 = (f32x4*)orow;

  float mx[kT], v0[kT];
#pragma unroll
  for (int t = 0; t < kT; ++t) {
    mx[t] = -INFINITY;
    v0[t] = 0.0f;
  }

  for (int v4 = tid; v4 < kV4; v4 += kThreads) {
    f32x4 x[NA];
#pragma unroll
    for (int n = 0; n < NUSE; ++n) x[n] = __builtin_nontemporal_load(&rows[n][v4]);
    const bool head = (v4 == 0);  // only tid 0, first iteration
#pragma unroll
    for (int t = 0; t < kT; ++t) {
      float ax = 0.0f, ay = 0.0f, az = 0.0f, aw = 0.0f;
#pragma unroll
      for (int n = 0; n < NUSE; ++n) {
        ax = fmaf(w[t][n], x[n].x, ax);
        ay = fmaf(w[t][n], x[n].y, ay);
        az = fmaf(w[t][n], x[n].z, az);
        aw = fmaf(w[t][n], x[n].w, aw);
      }
      if (head && m == 0) ax += w0[t];  // pad one-hot lands at (m=0,v=0)
      if (head) v0[t] = ax;
      mx[t] = fmaxf(mx[t], fmaxf(fmaxf(ax, ay), fmaxf(az, aw)));
      if (t == 0) {
        f32x4 o = {ax, ay, az, aw};
        __builtin_nontemporal_store(o, &orow4[v4]);
      }
    }
  }

  // Block max reduction per t: wave shuffle, then 4 wave results via LDS.
  __shared__ float red[kT][4];
  const int lane = tid & 63;
  const int wv = tid >> 6;
#pragma unroll
  for (int t = 0; t < kT; ++t) {
    float v = mx[t];
#pragma unroll
    for (int off = 32; off > 0; off >>= 1) v = fmaxf(v, __shfl_xor(v, off, 64));
    if (lane == 0) red[t][wv] = v;
  }
  __syncthreads();
  if (tid == 0) {
#pragma unroll
    for (int t = 0; t < kT; ++t) {
      float bm = fmaxf(fmaxf(red[t][0], red[t][1]), fmaxf(red[t][2], red[t][3]));
      // v0 attains the block max  <=>  argmax over v is 0 (first occurrence)
      flags[(b * kT + t) * kM + m] = (v0[t] >= bm) ? 1 : 0;
    }
  }
}

__global__ __launch_bounds__(kThreads) void pass1_kernel(
    const float* __restrict__ in, const float* __restrict__ tmpl,
    const int* __restrict__ spans, float* __restrict__ out,
    int* __restrict__ flags) {
  const int blk = blockIdx.x;
  const int b = blk >> 6;
  const int m = blk & 63;
  int span = spans[b];
  int nuse = span < 0 ? 0 : (span > kN ? kN : span);  // rows used: n < span
  const float* tw = tmpl + (size_t)b * kT * kS;
  float* orow = out + (size_t)(b * kM + m) * kV;
  switch (nuse) {
    case 0: pass1_body<0>(in, tw, orow, b, m, flags); break;
    case 1: pass1_body<1>(in, tw, orow, b, m, flags); break;
    case 2: pass1_body<2>(in, tw, orow, b, m, flags); break;
    case 3: pass1_body<3>(in, tw, orow, b, m, flags); break;
    case 4: pass1_body<4>(in, tw, orow, b, m, flags); break;
    case 5: pass1_body<5>(in, tw, orow, b, m, flags); break;
    case 6: pass1_body<6>(in, tw, orow, b, m, flags); break;
  }
}

// ---------------------------------------------------------------------------
// Patch: per (b,m) block. Recover len[t] = first m' with flag set (ballot),
// run the tiny sequential scan inline, then:
//   sel t==0  -> row already stored by pass1, return
//   unwritten -> zero the row
//   else      -> recompute the selected (t, src_row) row
// ---------------------------------------------------------------------------
__global__ __launch_bounds__(kThreads) void patch_kernel(
    const float* __restrict__ in, const float* __restrict__ tmpl,
    const int* __restrict__ spans, const int* __restrict__ flags,
    float* __restrict__ out) {
  const int blk = blockIdx.x;
  const int b = blk >> 6;
  const int m = blk & 63;
  const int tid = threadIdx.x;
  const int lane = tid & 63;

  __shared__ int slen[kT];
  if (tid < 64) {
    // lane j inspects flag[b][t][j]; ballot -> first set bit = len[t]
#pragma unroll
    for (int t = 0; t < kT; ++t) {
      int f = flags[(b * kT + t) * kM + lane];
      unsigned long long bal = __ballot(f != 0);
      if (lane == 0) slen[t] = bal ? (int)(__ffsll((long long)bal) - 1) : kM;
    }
  }
  __syncthreads();

  // sequential scan (cheap, every thread redundantly)
  int sel_t = -1, sel_row = 0, idx = 0;
#pragma unroll
  for (int t = 0; t < kT; ++t) {
    int L = slen[t];
    if (L > kM - idx) L = kM - idx;
    if (sel_t < 0 && m >= idx && m < idx + L) {
      sel_t = t;
      sel_row = m - idx;
    }
    idx += L;
  }

  if (sel_t == 0) return;  // t==0 => sel_row == m, already stored by pass1

  float* orow = out + (size_t)(b * kM + m) * kV;
  f32x4* orow4 = (f32x4*)orow;

  if (sel_t < 0) {  // never written by the scan -> zeros
    f32x4 z = {0.0f, 0.0f, 0.0f, 0.0f};
    for (int v4 = tid; v4 < kV4; v4 += kThreads)
      __builtin_nontemporal_store(z, &orow4[v4]);
    return;
  }

  const int t = sel_t;
  const int row = sel_row;
  int span = spans[b];
  int nuse = span < 0 ? 0 : (span > kN ? kN : span);
  const float* tw = tmpl + ((size_t)b * kT + t) * kS;
  const float w0 = tw[0];
  float w[kN];
  for (int n = 0; n < kN; ++n) w[n] = (n < nuse) ? tw[n + 1] : 0.0f;

  const f32x4* rows[kN];
  for (int n = 0; n < kN; ++n)
    rows[n] = (const f32x4*)(in + ((size_t)(b * kN + n) * kM + row) * kV);

  for (int v4 = tid; v4 < kV4; v4 += kThreads) {
    float ax = 0.0f, ay = 0.0f, az = 0.0f, aw = 0.0f;
    for (int n = 0; n < nuse; ++n) {
      f32x4 x = __builtin_nontemporal_load(&rows[n][v4]);
      ax = fmaf(w[n], x.x, ax);
      ay = fmaf(w[n], x.y, ay);
      az = fmaf(w[n], x.z, az);
      aw = fmaf(w[n], x.w, aw);
    }
    if (v4 == 0 && row == 0) ax += w0;
    f32x4 o = {ax, ay, az, aw};
    __builtin_nontemporal_store(o, &orow4[v4]);
  }
}

extern "C" void kernel_launch(void* const* d_in, const int* in_sizes, int n_in,
                              void* d_out, int out_size, void* d_ws,
                              size_t ws_size, hipStream_t stream) {
  const float* in = (const float*)d_in[0];     // [B,N,M,V] f32
  const float* tmpl = (const float*)d_in[1];   // [B,T,N+1] f32
  const int* spans = (const int*)d_in[2];      // [B] i32
  float* out = (float*)d_out;                  // [B,M,V] f32

  int* flags = (int*)d_ws;  // B*T*M ints, fully written by pass1

  hipLaunchKernelGGL(pass1_kernel, dim3(kB * kM), dim3(kThreads), 0, stream,
                     in, tmpl, spans, out, flags);
  hipLaunchKernelGGL(patch_kernel, dim3(kB * kM), dim3(kThreads), 0, stream,
                     in, tmpl, spans, flags, out);
}